// Round 11
// baseline (64.086 us; speedup 1.0000x reference)
//
#include <hip/hip_runtime.h>
#include <hip/hip_fp16.h>

typedef _Float16 f16x8 __attribute__((ext_vector_type(8)));
typedef _Float16 f16x4 __attribute__((ext_vector_type(4)));
typedef float f32x4 __attribute__((ext_vector_type(4)));
typedef int   i32x4 __attribute__((ext_vector_type(4)));

// ---------------------------------------------------------------------------
// prep_weights: 128 blocks x 256 threads
//   WcT  f16 [128][256]: row o<64 = W_s col o; row 64+o = mean_m W_lin col o
//   Wt16 f16 [64][256] : W_t transposed
//   bmean f32 [64]     : mean_m b_lin
// ---------------------------------------------------------------------------
__global__ void prep_weights(const float* __restrict__ W_lin, const float* __restrict__ b_lin,
                             const float* __restrict__ W_s, const float* __restrict__ W_t,
                             _Float16* __restrict__ WcT, _Float16* __restrict__ Wt16,
                             float* __restrict__ bmean) {
    int tid = blockIdx.x * 256 + threadIdx.x;    // 32768 threads
    if (tid < 16384) {
        int c = tid >> 6, o = tid & 63;
        WcT[o * 256 + c]  = (_Float16)W_s[c * 64 + o];
        Wt16[o * 256 + c] = (_Float16)W_t[c * 64 + o];
    } else {
        int t = tid - 16384;
        int c = t >> 6, o = t & 63;
        float s = 0.f;
        #pragma unroll 8
        for (int m = 0; m < 64; ++m) s += W_lin[m * 16384 + c * 64 + o];
        WcT[(64 + o) * 256 + c] = (_Float16)(s * (1.f / 64.f));
    }
    if (tid < 64) {
        float s = 0.f;
        #pragma unroll 8
        for (int m = 0; m < 64; ++m) s += b_lin[m * 64 + tid];
        bmean[tid] = s * (1.f / 64.f);
    }
}

// ---------------------------------------------------------------------------
// gemm_prep: 512 blocks x 256 threads (4 waves), 64 A-rows per block.
// B staged fragment-major in LDS (conflict-free ds_read_b128 at l*16+imm);
// one barrier; A rows read f32 upfront via NONTEMPORAL loads (streamed once,
// keep L2 for WcT/Wt16 + the Ppe/Et write-back), cvt f16 in-reg.
//  blocks 0..255  (src): Ppe row = per-4-col-group interleaved [pe(4)|pp(4)]:
//     col c: pe at (c>>2)*8+(c&3), pp at (c>>2)*8+4+(c&3)
//     pe = exp((source@W_s)[r][c]);  pp = (source@W_mean)[r][c] + bmean[c]
//  blocks 256..511 (tgt): Et[r][o] = exp((target@W_t)[r][o]+b_s[o]+b_t[o]) f32
// ---------------------------------------------------------------------------
__device__ __forceinline__ f16x8 cvt8nt(const float* p) {
    f32x4 x = __builtin_nontemporal_load((const f32x4*)p);
    f32x4 y = __builtin_nontemporal_load((const f32x4*)(p + 4));
    f16x8 h;
    h[0] = (_Float16)x[0]; h[1] = (_Float16)x[1]; h[2] = (_Float16)x[2]; h[3] = (_Float16)x[3];
    h[4] = (_Float16)y[0]; h[5] = (_Float16)y[1]; h[6] = (_Float16)y[2]; h[7] = (_Float16)y[3];
    return h;
}

__global__ __launch_bounds__(256, 2)
void gemm_prep(const float* __restrict__ source, const float* __restrict__ target,
               const _Float16* __restrict__ WcT, const _Float16* __restrict__ Wt16,
               const float* __restrict__ bmean, const float* __restrict__ b_s,
               const float* __restrict__ b_t,
               _Float16* __restrict__ Ppe, float* __restrict__ Et) {
    __shared__ _Float16 lds[32768];   // SRC path uses 64 KiB, TGT 32 KiB

    const int tid = threadIdx.x;
    const int w = tid >> 6, l = tid & 63;
    const int l15 = l & 15, lq = l >> 4;
    const int b = blockIdx.x;

    if (b < 256) {
        // ---------------- SRC path ----------------
        const int rb = b * 64;
        const float* arow = source + (size_t)(rb + w * 16 + l15) * 256;
        f16x8 af[8];
        #pragma unroll
        for (int s = 0; s < 8; ++s) af[s] = cvt8nt(arow + s * 32 + lq * 8);

        #pragma unroll
        for (int i = 0; i < 16; ++i) {
            int c = i * 256 + tid;                   // 4096 chunks
            int fi = c >> 6, lane = c & 63;
            int nt = fi >> 3, s = fi & 7;
            f16x8 v = *(const f16x8*)(WcT + (nt * 16 + (lane & 15)) * 256 + s * 32 + (lane >> 4) * 8);
            *(f16x8*)((char*)lds + c * 16) = v;
        }
        __syncthreads();

        const char* bb = (const char*)lds + l * 16;
        f32x4 acc[8] = {};
        #pragma unroll
        for (int s = 0; s < 8; ++s) {
            #pragma unroll
            for (int nt = 0; nt < 8; ++nt) {
                f16x8 bf = *(const f16x8*)(bb + nt * 8192 + s * 1024);
                acc[nt] = __builtin_amdgcn_mfma_f32_16x16x32_f16(af[s], bf, acc[nt], 0, 0, 0);
            }
        }

        float bmv[4];
        #pragma unroll
        for (int nt = 0; nt < 4; ++nt) bmv[nt] = bmean[nt * 16 + l15];
        // interleaved position for col c = nt*16 + l15:
        //   pe: nt*32 + (l15>>2)*8 + (l15&3);  pp: +4
        const int ip = (l15 >> 2) * 8 + (l15 & 3);
        #pragma unroll
        for (int j = 0; j < 4; ++j) {
            int row = rb + w * 16 + lq * 4 + j;
            #pragma unroll
            for (int nt = 0; nt < 4; ++nt) {
                Ppe[row * 128 + nt * 32 + ip]     = (_Float16)__expf(acc[nt][j]);
                Ppe[row * 128 + nt * 32 + ip + 4] = (_Float16)(acc[nt + 4][j] + bmv[nt]);
            }
        }
    } else {
        // ---------------- TGT path ----------------
        const int rb = (b - 256) * 64;
        const float* arow = target + (size_t)(rb + w * 16 + l15) * 256;
        f16x8 af[8];
        #pragma unroll
        for (int s = 0; s < 8; ++s) af[s] = cvt8nt(arow + s * 32 + lq * 8);

        #pragma unroll
        for (int i = 0; i < 8; ++i) {
            int c = i * 256 + tid;                   // 2048 chunks
            int fi = c >> 6, lane = c & 63;
            int nt = fi >> 3, s = fi & 7;
            f16x8 v = *(const f16x8*)(Wt16 + (nt * 16 + (lane & 15)) * 256 + s * 32 + (lane >> 4) * 8);
            *(f16x8*)((char*)lds + c * 16) = v;
        }
        __syncthreads();

        const char* bb = (const char*)lds + l * 16;
        f32x4 acc[4] = {};
        #pragma unroll
        for (int s = 0; s < 8; ++s) {
            #pragma unroll
            for (int nt = 0; nt < 4; ++nt) {
                f16x8 bf = *(const f16x8*)(bb + nt * 8192 + s * 1024);
                acc[nt] = __builtin_amdgcn_mfma_f32_16x16x32_f16(af[s], bf, acc[nt], 0, 0, 0);
            }
        }

        float bsv[4];
        #pragma unroll
        for (int nt = 0; nt < 4; ++nt) {
            int col = nt * 16 + l15;
            bsv[nt] = b_s[col] + b_t[col];
        }
        #pragma unroll
        for (int j = 0; j < 4; ++j) {
            int row = rb + w * 16 + lq * 4 + j;
            #pragma unroll
            for (int nt = 0; nt < 4; ++nt)
                Et[row * 64 + nt * 16 + l15] = __expf(acc[nt][j] + bsv[nt]);
        }
    }
}

// ---------------------------------------------------------------------------
// epilogue: 1024 blocks x 256 threads, grid-stride x2 -> single balanced
// occupancy round (1024 <= 5 blocks/CU x 256 CU). TWO nodes per wave per it.
// Row map r = n*32 + lq*8 + g; nb loaded as NONTEMPORAL int4 (streamed once);
// Et NONTEMPORAL f32x4 (streamed once). One f16x8 gather per neighbor
// (interleaved [pe4|pp4] layout, regular loads -> L2-resident table).
// Output stores NONTEMPORAL (134 MB stream must not evict Ppe from L2).
// out[r][o] = pe[nb][o]*Et[n][o] / sum_o(pe*Et) * pp[nb][o]
// ---------------------------------------------------------------------------
__global__ __launch_bounds__(256, 5)
void epilogue(const int* __restrict__ neighbors, const _Float16* __restrict__ Ppe,
              const float* __restrict__ Et, float* __restrict__ out) {
    const int tid = threadIdx.x;
    const int w = tid >> 6, l = tid & 63;
    const int lq = l >> 4, l15 = l & 15;
    const int co = l15 * 4;
    const int ro = l15 * 8;                     // elem offset of col-group

    #pragma unroll
    for (int it = 0; it < 2; ++it) {
        const int n0 = (blockIdx.x + it * 1024) * 8 + w * 2;   // nodes n0, n0+1

        i32x4 na0 = __builtin_nontemporal_load((const i32x4*)(neighbors + n0 * 32 + lq * 8));
        i32x4 na1 = __builtin_nontemporal_load((const i32x4*)(neighbors + n0 * 32 + lq * 8 + 4));
        i32x4 nc0 = __builtin_nontemporal_load((const i32x4*)(neighbors + (n0 + 1) * 32 + lq * 8));
        i32x4 nc1 = __builtin_nontemporal_load((const i32x4*)(neighbors + (n0 + 1) * 32 + lq * 8 + 4));

        f32x4 et0 = __builtin_nontemporal_load((const f32x4*)(Et + n0 * 64 + co));
        f32x4 et1 = __builtin_nontemporal_load((const f32x4*)(Et + (n0 + 1) * 64 + co));

        f16x8 q0[8], q1[8];
        #pragma unroll
        for (int g = 0; g < 4; ++g) q0[g]     = *(const f16x8*)(Ppe + na0[g] * 128 + ro);
        #pragma unroll
        for (int g = 0; g < 4; ++g) q0[4 + g] = *(const f16x8*)(Ppe + na1[g] * 128 + ro);
        #pragma unroll
        for (int g = 0; g < 4; ++g) q1[g]     = *(const f16x8*)(Ppe + nc0[g] * 128 + ro);
        #pragma unroll
        for (int g = 0; g < 4; ++g) q1[4 + g] = *(const f16x8*)(Ppe + nc1[g] * 128 + ro);

        #pragma unroll
        for (int g = 0; g < 8; ++g) {
            float w0 = (float)q0[g][0] * et0[0];
            float w1 = (float)q0[g][1] * et0[1];
            float w2 = (float)q0[g][2] * et0[2];
            float w3 = (float)q0[g][3] * et0[3];
            float s = (w0 + w1) + (w2 + w3);
            s += __shfl_xor(s, 1);
            s += __shfl_xor(s, 2);
            s += __shfl_xor(s, 4);
            s += __shfl_xor(s, 8);
            float inv = 1.0f / s;
            f32x4 o;
            o[0] = w0 * inv * (float)q0[g][4];
            o[1] = w1 * inv * (float)q0[g][5];
            o[2] = w2 * inv * (float)q0[g][6];
            o[3] = w3 * inv * (float)q0[g][7];
            __builtin_nontemporal_store(o, (f32x4*)(out + (size_t)(n0 * 32 + lq * 8 + g) * 64 + co));
        }
        #pragma unroll
        for (int g = 0; g < 8; ++g) {
            float w0 = (float)q1[g][0] * et1[0];
            float w1 = (float)q1[g][1] * et1[1];
            float w2 = (float)q1[g][2] * et1[2];
            float w3 = (float)q1[g][3] * et1[3];
            float s = (w0 + w1) + (w2 + w3);
            s += __shfl_xor(s, 1);
            s += __shfl_xor(s, 2);
            s += __shfl_xor(s, 4);
            s += __shfl_xor(s, 8);
            float inv = 1.0f / s;
            f32x4 o;
            o[0] = w0 * inv * (float)q1[g][4];
            o[1] = w1 * inv * (float)q1[g][5];
            o[2] = w2 * inv * (float)q1[g][6];
            o[3] = w3 * inv * (float)q1[g][7];
            __builtin_nontemporal_store(o, (f32x4*)(out + (size_t)((n0 + 1) * 32 + lq * 8 + g) * 64 + co));
        }
    }
}

// ---------------------------------------------------------------------------
extern "C" void kernel_launch(void* const* d_in, const int* in_sizes, int n_in,
                              void* d_out, int out_size, void* d_ws, size_t ws_size,
                              hipStream_t stream) {
    const float* source    = (const float*)d_in[0];
    const float* target    = (const float*)d_in[1];
    const int*   neighbors = (const int*)d_in[2];
    const float* W_lin     = (const float*)d_in[3];
    const float* b_lin     = (const float*)d_in[4];
    const float* W_s       = (const float*)d_in[5];
    const float* b_s       = (const float*)d_in[6];
    const float* W_t       = (const float*)d_in[7];
    const float* b_t       = (const float*)d_in[8];

    char* ws = (char*)d_ws;
    _Float16* Ppe   = (_Float16*)ws;                          // 4 MiB
    float*    Et    = (float*)(ws + (4u << 20));              // 4 MiB
    _Float16* WcT   = (_Float16*)(ws + (8u << 20));           // 64 KiB
    _Float16* Wt16  = (_Float16*)(ws + (8u << 20) + 65536);   // 32 KiB
    float*    bmean = (float*)(ws + (8u << 20) + 98304);      // 256 B
    float*    out   = (float*)d_out;

    prep_weights<<<128, 256, 0, stream>>>(W_lin, b_lin, W_s, W_t, WcT, Wt16, bmean);
    gemm_prep<<<512, 256, 0, stream>>>(source, target, WcT, Wt16, bmean, b_s, b_t,
                                       Ppe, Et);
    epilogue<<<1024, 256, 0, stream>>>(neighbors, Ppe, Et, out);
}

// Round 12
// 47.581 us; speedup vs baseline: 1.3469x; 1.3469x over previous
//
#include <hip/hip_runtime.h>
#include <hip/hip_fp16.h>

typedef _Float16 f16x8 __attribute__((ext_vector_type(8)));
typedef _Float16 f16x4 __attribute__((ext_vector_type(4)));
typedef float f32x4 __attribute__((ext_vector_type(4)));
typedef int   i32x4 __attribute__((ext_vector_type(4)));

// ---------------------------------------------------------------------------
// prep_weights: 128 blocks x 256 threads
//   WcT  f16 [128][256]: row o<64 = W_s col o; row 64+o = mean_m W_lin col o
//   Wt16 f16 [64][256] : W_t transposed
//   bmean f32 [64]     : mean_m b_lin
// ---------------------------------------------------------------------------
__global__ void prep_weights(const float* __restrict__ W_lin, const float* __restrict__ b_lin,
                             const float* __restrict__ W_s, const float* __restrict__ W_t,
                             _Float16* __restrict__ WcT, _Float16* __restrict__ Wt16,
                             float* __restrict__ bmean) {
    int tid = blockIdx.x * 256 + threadIdx.x;    // 32768 threads
    if (tid < 16384) {
        int c = tid >> 6, o = tid & 63;
        WcT[o * 256 + c]  = (_Float16)W_s[c * 64 + o];
        Wt16[o * 256 + c] = (_Float16)W_t[c * 64 + o];
    } else {
        int t = tid - 16384;
        int c = t >> 6, o = t & 63;
        float s = 0.f;
        #pragma unroll 8
        for (int m = 0; m < 64; ++m) s += W_lin[m * 16384 + c * 64 + o];
        WcT[(64 + o) * 256 + c] = (_Float16)(s * (1.f / 64.f));
    }
    if (tid < 64) {
        float s = 0.f;
        #pragma unroll 8
        for (int m = 0; m < 64; ++m) s += b_lin[m * 64 + tid];
        bmean[tid] = s * (1.f / 64.f);
    }
}

// ---------------------------------------------------------------------------
// gemm_prep: 512 blocks x 256 threads (4 waves), 64 A-rows per block.
// B staged fragment-major in LDS (conflict-free ds_read_b128 at l*16+imm);
// one barrier; A rows read f32 upfront with REGULAR loads (r11 lesson:
// nontemporal loads at low occupancy are latency-bound), cvt f16 in-reg.
//  blocks 0..255  (src): Ppe row = per-4-col-group interleaved [pe(4)|pp(4)]:
//     col c: pe at (c>>2)*8+(c&3), pp at (c>>2)*8+4+(c&3)
//     pe = exp((source@W_s)[r][c]);  pp = (source@W_mean)[r][c] + bmean[c]
//  blocks 256..511 (tgt): Et[r][o] = exp((target@W_t)[r][o]+b_s[o]+b_t[o]) f32
// ---------------------------------------------------------------------------
__device__ __forceinline__ f16x8 cvt8(const float* p) {
    f32x4 x = *(const f32x4*)p;
    f32x4 y = *(const f32x4*)(p + 4);
    f16x8 h;
    h[0] = (_Float16)x[0]; h[1] = (_Float16)x[1]; h[2] = (_Float16)x[2]; h[3] = (_Float16)x[3];
    h[4] = (_Float16)y[0]; h[5] = (_Float16)y[1]; h[6] = (_Float16)y[2]; h[7] = (_Float16)y[3];
    return h;
}

__global__ __launch_bounds__(256, 2)
void gemm_prep(const float* __restrict__ source, const float* __restrict__ target,
               const _Float16* __restrict__ WcT, const _Float16* __restrict__ Wt16,
               const float* __restrict__ bmean, const float* __restrict__ b_s,
               const float* __restrict__ b_t,
               _Float16* __restrict__ Ppe, float* __restrict__ Et) {
    __shared__ _Float16 lds[32768];   // SRC path uses 64 KiB, TGT 32 KiB

    const int tid = threadIdx.x;
    const int w = tid >> 6, l = tid & 63;
    const int l15 = l & 15, lq = l >> 4;
    const int b = blockIdx.x;

    if (b < 256) {
        // ---------------- SRC path ----------------
        const int rb = b * 64;
        const float* arow = source + (size_t)(rb + w * 16 + l15) * 256;
        f16x8 af[8];
        #pragma unroll
        for (int s = 0; s < 8; ++s) af[s] = cvt8(arow + s * 32 + lq * 8);

        #pragma unroll
        for (int i = 0; i < 16; ++i) {
            int c = i * 256 + tid;                   // 4096 chunks
            int fi = c >> 6, lane = c & 63;
            int nt = fi >> 3, s = fi & 7;
            f16x8 v = *(const f16x8*)(WcT + (nt * 16 + (lane & 15)) * 256 + s * 32 + (lane >> 4) * 8);
            *(f16x8*)((char*)lds + c * 16) = v;
        }
        __syncthreads();

        const char* bb = (const char*)lds + l * 16;
        f32x4 acc[8] = {};
        #pragma unroll
        for (int s = 0; s < 8; ++s) {
            #pragma unroll
            for (int nt = 0; nt < 8; ++nt) {
                f16x8 bf = *(const f16x8*)(bb + nt * 8192 + s * 1024);
                acc[nt] = __builtin_amdgcn_mfma_f32_16x16x32_f16(af[s], bf, acc[nt], 0, 0, 0);
            }
        }

        float bmv[4];
        #pragma unroll
        for (int nt = 0; nt < 4; ++nt) bmv[nt] = bmean[nt * 16 + l15];
        // interleaved position for col c = nt*16 + l15:
        //   pe: nt*32 + (l15>>2)*8 + (l15&3);  pp: +4
        const int ip = (l15 >> 2) * 8 + (l15 & 3);
        #pragma unroll
        for (int j = 0; j < 4; ++j) {
            int row = rb + w * 16 + lq * 4 + j;
            #pragma unroll
            for (int nt = 0; nt < 4; ++nt) {
                Ppe[row * 128 + nt * 32 + ip]     = (_Float16)__expf(acc[nt][j]);
                Ppe[row * 128 + nt * 32 + ip + 4] = (_Float16)(acc[nt + 4][j] + bmv[nt]);
            }
        }
    } else {
        // ---------------- TGT path ----------------
        const int rb = (b - 256) * 64;
        const float* arow = target + (size_t)(rb + w * 16 + l15) * 256;
        f16x8 af[8];
        #pragma unroll
        for (int s = 0; s < 8; ++s) af[s] = cvt8(arow + s * 32 + lq * 8);

        #pragma unroll
        for (int i = 0; i < 8; ++i) {
            int c = i * 256 + tid;                   // 2048 chunks
            int fi = c >> 6, lane = c & 63;
            int nt = fi >> 3, s = fi & 7;
            f16x8 v = *(const f16x8*)(Wt16 + (nt * 16 + (lane & 15)) * 256 + s * 32 + (lane >> 4) * 8);
            *(f16x8*)((char*)lds + c * 16) = v;
        }
        __syncthreads();

        const char* bb = (const char*)lds + l * 16;
        f32x4 acc[4] = {};
        #pragma unroll
        for (int s = 0; s < 8; ++s) {
            #pragma unroll
            for (int nt = 0; nt < 4; ++nt) {
                f16x8 bf = *(const f16x8*)(bb + nt * 8192 + s * 1024);
                acc[nt] = __builtin_amdgcn_mfma_f32_16x16x32_f16(af[s], bf, acc[nt], 0, 0, 0);
            }
        }

        float bsv[4];
        #pragma unroll
        for (int nt = 0; nt < 4; ++nt) {
            int col = nt * 16 + l15;
            bsv[nt] = b_s[col] + b_t[col];
        }
        #pragma unroll
        for (int j = 0; j < 4; ++j) {
            int row = rb + w * 16 + lq * 4 + j;
            #pragma unroll
            for (int nt = 0; nt < 4; ++nt)
                Et[row * 64 + nt * 16 + l15] = __expf(acc[nt][j] + bsv[nt]);
        }
    }
}

// ---------------------------------------------------------------------------
// epilogue: 2048 blocks x 256 threads; TWO target nodes per wave.
// Row map r = n*32 + lq*8 + g (g=0..7): per-lane CONSECUTIVE neighbor
// indices -> nb loaded as int4 x2 per node (REGULAR loads). One f16x8 gather
// per neighbor (interleaved [pe4|pp4] layout). Output stores NONTEMPORAL
// (134 MB stream must not evict Ppe from L2 — r10: -5.2 us).
// __launch_bounds__(256,4): 2048 blocks / (4*256) = exactly 2 balanced
// rounds; VGPR cap 128 keeps the 16-gather window un-rematerialized.
// out[r][o] = pe[nb][o]*Et[n][o] / sum_o(pe*Et) * pp[nb][o]
// ---------------------------------------------------------------------------
__global__ __launch_bounds__(256, 4)
void epilogue(const int* __restrict__ neighbors, const _Float16* __restrict__ Ppe,
              const float* __restrict__ Et, float* __restrict__ out) {
    const int tid = threadIdx.x;
    const int w = tid >> 6, l = tid & 63;
    const int lq = l >> 4, l15 = l & 15;
    const int n0 = blockIdx.x * 8 + w * 2;      // this wave: n0, n0+1
    const int co = l15 * 4;
    const int ro = l15 * 8;                     // elem offset of col-group

    i32x4 na0 = *(const i32x4*)(neighbors + n0 * 32 + lq * 8);
    i32x4 na1 = *(const i32x4*)(neighbors + n0 * 32 + lq * 8 + 4);
    i32x4 nc0 = *(const i32x4*)(neighbors + (n0 + 1) * 32 + lq * 8);
    i32x4 nc1 = *(const i32x4*)(neighbors + (n0 + 1) * 32 + lq * 8 + 4);

    f32x4 et0 = *(const f32x4*)(Et + n0 * 64 + co);
    f32x4 et1 = *(const f32x4*)(Et + (n0 + 1) * 64 + co);

    f16x8 q0[8], q1[8];
    #pragma unroll
    for (int g = 0; g < 4; ++g) q0[g]     = *(const f16x8*)(Ppe + na0[g] * 128 + ro);
    #pragma unroll
    for (int g = 0; g < 4; ++g) q0[4 + g] = *(const f16x8*)(Ppe + na1[g] * 128 + ro);
    #pragma unroll
    for (int g = 0; g < 4; ++g) q1[g]     = *(const f16x8*)(Ppe + nc0[g] * 128 + ro);
    #pragma unroll
    for (int g = 0; g < 4; ++g) q1[4 + g] = *(const f16x8*)(Ppe + nc1[g] * 128 + ro);

    #pragma unroll
    for (int g = 0; g < 8; ++g) {
        float w0 = (float)q0[g][0] * et0[0];
        float w1 = (float)q0[g][1] * et0[1];
        float w2 = (float)q0[g][2] * et0[2];
        float w3 = (float)q0[g][3] * et0[3];
        float s = (w0 + w1) + (w2 + w3);
        s += __shfl_xor(s, 1);
        s += __shfl_xor(s, 2);
        s += __shfl_xor(s, 4);
        s += __shfl_xor(s, 8);
        float inv = 1.0f / s;
        f32x4 o;
        o[0] = w0 * inv * (float)q0[g][4];
        o[1] = w1 * inv * (float)q0[g][5];
        o[2] = w2 * inv * (float)q0[g][6];
        o[3] = w3 * inv * (float)q0[g][7];
        __builtin_nontemporal_store(o, (f32x4*)(out + (size_t)(n0 * 32 + lq * 8 + g) * 64 + co));
    }
    #pragma unroll
    for (int g = 0; g < 8; ++g) {
        float w0 = (float)q1[g][0] * et1[0];
        float w1 = (float)q1[g][1] * et1[1];
        float w2 = (float)q1[g][2] * et1[2];
        float w3 = (float)q1[g][3] * et1[3];
        float s = (w0 + w1) + (w2 + w3);
        s += __shfl_xor(s, 1);
        s += __shfl_xor(s, 2);
        s += __shfl_xor(s, 4);
        s += __shfl_xor(s, 8);
        float inv = 1.0f / s;
        f32x4 o;
        o[0] = w0 * inv * (float)q1[g][4];
        o[1] = w1 * inv * (float)q1[g][5];
        o[2] = w2 * inv * (float)q1[g][6];
        o[3] = w3 * inv * (float)q1[g][7];
        __builtin_nontemporal_store(o, (f32x4*)(out + (size_t)((n0 + 1) * 32 + lq * 8 + g) * 64 + co));
    }
}

// ---------------------------------------------------------------------------
extern "C" void kernel_launch(void* const* d_in, const int* in_sizes, int n_in,
                              void* d_out, int out_size, void* d_ws, size_t ws_size,
                              hipStream_t stream) {
    const float* source    = (const float*)d_in[0];
    const float* target    = (const float*)d_in[1];
    const int*   neighbors = (const int*)d_in[2];
    const float* W_lin     = (const float*)d_in[3];
    const float* b_lin     = (const float*)d_in[4];
    const float* W_s       = (const float*)d_in[5];
    const float* b_s       = (const float*)d_in[6];
    const float* W_t       = (const float*)d_in[7];
    const float* b_t       = (const float*)d_in[8];

    char* ws = (char*)d_ws;
    _Float16* Ppe   = (_Float16*)ws;                          // 4 MiB
    float*    Et    = (float*)(ws + (4u << 20));              // 4 MiB
    _Float16* WcT   = (_Float16*)(ws + (8u << 20));           // 64 KiB
    _Float16* Wt16  = (_Float16*)(ws + (8u << 20) + 65536);   // 32 KiB
    float*    bmean = (float*)(ws + (8u << 20) + 98304);      // 256 B
    float*    out   = (float*)d_out;

    prep_weights<<<128, 256, 0, stream>>>(W_lin, b_lin, W_s, W_t, WcT, Wt16, bmean);
    gemm_prep<<<512, 256, 0, stream>>>(source, target, WcT, Wt16, bmean, b_s, b_t,
                                       Ppe, Et);
    epilogue<<<2048, 256, 0, stream>>>(neighbors, Ppe, Et, out);
}